// Round 4
// baseline (601.304 us; speedup 1.0000x reference)
//
#include <hip/hip_runtime.h>

// Problem constants (from reference): B=256, F=300, JC=1600, NC=60
#define B_   256
#define F_   300
#define JC_  1600
#define NC_  60
#define J4_  400      // JC/4 : float4 elements per row
#define CH4_ 100      // float4 elements per j-chunk (4 chunks of 400 floats)
#define FT_  64       // frames per tile
#define NT_  5        // ceil(F/FT)

// out[b,n] = bias[n]  (d_out is poisoned before every timed launch)
__global__ __launch_bounds__(256) void ar_init_out(const float* __restrict__ bias,
                                                   float* __restrict__ out) {
    int i = blockIdx.x * 256 + threadIdx.x;
    if (i < B_ * NC_) out[i] = bias[i % NC_];
}

// One block per (sample b, frame-tile t, j-chunk jc).
// Phase 1: sum x over this tile's valid frames for a 400-float slice (only
// valid frames are read). Phase 2: push the partial sum through W scaled by
// 1/len (GEMV is linear, so per-tile partials compose by addition) and
// atomicAdd into out.
__global__ __launch_bounds__(128) void ar_pool_gemv(const float* __restrict__ x,
                                                    const int*   __restrict__ lengths,
                                                    const float* __restrict__ W,
                                                    float*       __restrict__ out) {
    __shared__ float pl[CH4_ * 4];   // this chunk's partial pooled slice (400 floats)
    __shared__ float ps[64];         // wave-1 GEMV partials

    const int b   = blockIdx.x;
    const int t   = blockIdx.y;      // 0..NT_-1
    const int jc  = blockIdx.z;      // 0..3
    const int tid = threadIdx.x;

    int len = lengths[b];
    if (len < 1) len = 1;            // cnt<=1 edge case == mean over frame 0 only
    const int f0 = t * FT_;
    if (f0 >= len) return;           // tile fully past the valid prefix (uniform exit)
    const int fend  = (f0 + FT_ < len) ? (f0 + FT_) : len;
    const float scale = 1.0f / (float)len;

    // ---- Phase 1: partial-sum pooling (100 float4 lanes active) ----
    if (tid < CH4_) {
        const float4* xr = reinterpret_cast<const float4*>(x)
                         + (size_t)b * F_ * J4_ + jc * CH4_ + tid;
        float4 a0 = make_float4(0.f, 0.f, 0.f, 0.f);
        float4 a1 = a0, a2 = a0, a3 = a0;
        int f = f0;
        for (; f + 4 <= fend; f += 4) {
            float4 v0 = xr[(size_t)(f + 0) * J4_];
            float4 v1 = xr[(size_t)(f + 1) * J4_];
            float4 v2 = xr[(size_t)(f + 2) * J4_];
            float4 v3 = xr[(size_t)(f + 3) * J4_];
            a0.x += v0.x; a0.y += v0.y; a0.z += v0.z; a0.w += v0.w;
            a1.x += v1.x; a1.y += v1.y; a1.z += v1.z; a1.w += v1.w;
            a2.x += v2.x; a2.y += v2.y; a2.z += v2.z; a2.w += v2.w;
            a3.x += v3.x; a3.y += v3.y; a3.z += v3.z; a3.w += v3.w;
        }
        for (; f < fend; ++f) {
            float4 v = xr[(size_t)f * J4_];
            a0.x += v.x; a0.y += v.y; a0.z += v.z; a0.w += v.w;
        }
        float4 s;
        s.x = (a0.x + a1.x + a2.x + a3.x) * scale;
        s.y = (a0.y + a1.y + a2.y + a3.y) * scale;
        s.z = (a0.z + a1.z + a2.z + a3.z) * scale;
        s.w = (a0.w + a1.w + a2.w + a3.w) * scale;
        reinterpret_cast<float4*>(pl)[tid] = s;
    }
    __syncthreads();

    // ---- Phase 2: partial GEMV of this 400-row slice of W ----
    // wave 0 handles rows [0,200), wave 1 handles rows [200,400);
    // wave 1 parks its partials in shared, wave 0 issues ONE atomic per n.
    const int wv = tid >> 6;         // 0 or 1
    const int n  = tid & 63;         // output class lane
    float s = 0.f;
    if (n < NC_) {
        const float* Wp = W + (size_t)(jc * (CH4_ * 4) + wv * 200) * NC_ + n;
        const float* pp = pl + wv * 200;
        #pragma unroll 8
        for (int j = 0; j < 200; j += 2) {
            s += pp[j]     * Wp[(size_t)(j)     * NC_];
            s += pp[j + 1] * Wp[(size_t)(j + 1) * NC_];
        }
    }
    if (wv == 1 && n < NC_) ps[n] = s;
    __syncthreads();
    if (wv == 0 && n < NC_) atomicAdd(&out[b * NC_ + n], s + ps[n]);
}

extern "C" void kernel_launch(void* const* d_in, const int* in_sizes, int n_in,
                              void* d_out, int out_size, void* d_ws, size_t ws_size,
                              hipStream_t stream) {
    const float* x       = (const float*)d_in[0];   // [B, F, JC] f32
    const int*   lengths = (const int*)  d_in[1];   // [B] i32
    const float* W       = (const float*)d_in[2];   // [JC, NC] f32
    const float* bias    = (const float*)d_in[3];   // [NC] f32
    float*       out     = (float*)d_out;           // [B, NC] f32

    ar_init_out<<<dim3((B_ * NC_ + 255) / 256), 256, 0, stream>>>(bias, out);
    ar_pool_gemv<<<dim3(B_, NT_, 4), 128, 0, stream>>>(x, lengths, W, out);
}